// Round 1
// baseline (325.498 us; speedup 1.0000x reference)
//
#include <hip/hip_runtime.h>
#include <cstdint>

#define TOKENS 16384   // b*l = 4*4096
#define DIM 1024
#define NQ 1040        // 16 heads * 65 q-slots
#define NK 1024        // 16 * 64
#define NTOT 3088      // NQ + NK + NK (q | k | v)
#define NPAD 3200      // next multiple of 128

typedef __bf16 bf16_t;
typedef bf16_t bf16x8 __attribute__((ext_vector_type(8)));
typedef float f32x4 __attribute__((ext_vector_type(4)));

static __device__ __forceinline__ float bf2f(unsigned short u) {
    union { unsigned int i; float f; } v; v.i = ((unsigned int)u) << 16; return v.f;
}
static __device__ __forceinline__ unsigned short f2bf(float f) {
    unsigned int u = __float_as_uint(f);
    unsigned int r = u + 0x7FFFu + ((u >> 16) & 1u);   // RNE
    return (unsigned short)(r >> 16);
}

// async global->LDS, 16B per lane; LDS dest is wave-uniform base + lane*16B.
static __device__ __forceinline__ void gload_lds16(const void* g, void* l) {
    __builtin_amdgcn_global_load_lds(
        (__attribute__((address_space(1))) void*)(uintptr_t)g,
        (__attribute__((address_space(3))) void*)(unsigned int)(uintptr_t)l,
        16, 0, 0);
}

// ---------------- cast kernels ----------------
__global__ __launch_bounds__(256) void k_cast(const float* __restrict__ in,
                                              unsigned short* __restrict__ out, int n4) {
    int i = blockIdx.x * 256 + threadIdx.x;
    if (i >= n4) return;
    float4 v = ((const float4*)in)[i];
    ushort4 o;
    o.x = f2bf(v.x); o.y = f2bf(v.y); o.z = f2bf(v.z); o.w = f2bf(v.w);
    ((ushort4*)out)[i] = o;
}

// Build Wall[NPAD][DIM] bf16 = rows: Wq (1040) | Wk (1024) | Wv (1024) | zeros (112)
__global__ __launch_bounds__(256) void k_build_wall(const float* __restrict__ Wq,
                                                    const float* __restrict__ Wk,
                                                    const float* __restrict__ Wv,
                                                    unsigned short* __restrict__ Wall) {
    int i = blockIdx.x * 256 + threadIdx.x;       // over NPAD*DIM/4
    if (i >= NPAD * DIM / 4) return;
    int c4 = i & 255;          // DIM/4 = 256
    int r  = i >> 8;
    float4 v;
    if (r < NQ)              v = ((const float4*)Wq)[r * 256 + c4];
    else if (r < NQ + NK)    v = ((const float4*)Wk)[(r - NQ) * 256 + c4];
    else if (r < NTOT)       v = ((const float4*)Wv)[(r - (NQ + NK)) * 256 + c4];
    else                     v = make_float4(0.f, 0.f, 0.f, 0.f);
    ushort4 o;
    o.x = f2bf(v.x); o.y = f2bf(v.y); o.z = f2bf(v.z); o.w = f2bf(v.w);
    ((ushort4*)Wall)[i] = o;
}

// ---------------- bf16 MFMA GEMM: C[M,N] = A[M,K] * Bt[N,K]^T ----------------
// 128x128 tile, BK=32, 4 waves, global_load_lds staging (m97 structure).
template<int ADD_BIAS, int OUT_F32>
__global__ __launch_bounds__(256) void k_gemm(const unsigned short* __restrict__ A, int lda,
                                              const unsigned short* __restrict__ Bt, int ldb,
                                              void* __restrict__ Cout, int ldc, int nstore,
                                              const float* __restrict__ bias, int K) {
    __shared__ unsigned short Al[128 * 32];
    __shared__ unsigned short Bl[128 * 32];
    const int tid  = threadIdx.x;
    const int wid  = tid >> 6;
    const int lane = tid & 63;
    const int tm = blockIdx.y * 128;
    const int tn = blockIdx.x * 128;

    // staging: each wave fills 2 chunks (16 rows x 32 cols) of A and of B
    const int srow = lane >> 2;            // 0..15
    const int scol = (lane & 3) * 8;       // 0,8,16,24
    const unsigned short* Ag0 = A + (size_t)(tm + wid * 32 + srow) * lda + scol;
    const unsigned short* Ag1 = Ag0 + (size_t)16 * lda;
    const unsigned short* Bg0 = Bt + (size_t)(tn + wid * 32 + srow) * ldb + scol;
    const unsigned short* Bg1 = Bg0 + (size_t)16 * ldb;
    unsigned short* Al0 = &Al[(wid * 2 + 0) * 512];
    unsigned short* Al1 = &Al[(wid * 2 + 1) * 512];
    unsigned short* Bl0 = &Bl[(wid * 2 + 0) * 512];
    unsigned short* Bl1 = &Bl[(wid * 2 + 1) * 512];

    const int fr = lane & 15;
    const int fq = lane >> 4;
    const int wr = (wid >> 1) * 64;
    const int wc = (wid & 1) * 64;

    f32x4 acc[4][4] = {};

    for (int k0 = 0; k0 < K; k0 += 32) {
        gload_lds16(Ag0 + k0, Al0);
        gload_lds16(Ag1 + k0, Al1);
        gload_lds16(Bg0 + k0, Bl0);
        gload_lds16(Bg1 + k0, Bl1);
        __syncthreads();   // drains vmcnt(0) -> LDS tiles complete
        bf16x8 af[4], bfv[4];
#pragma unroll
        for (int m = 0; m < 4; ++m)
            af[m] = *(const bf16x8*)&Al[(wr + m * 16 + fr) * 32 + fq * 8];
#pragma unroll
        for (int n = 0; n < 4; ++n)
            bfv[n] = *(const bf16x8*)&Bl[(wc + n * 16 + fr) * 32 + fq * 8];
#pragma unroll
        for (int m = 0; m < 4; ++m)
#pragma unroll
            for (int n = 0; n < 4; ++n)
                acc[m][n] = __builtin_amdgcn_mfma_f32_16x16x32_bf16(af[m], bfv[n], acc[m][n], 0, 0, 0);
        __syncthreads();
    }

#pragma unroll
    for (int m = 0; m < 4; ++m) {
        const int row0 = tm + wr + m * 16 + fq * 4;
#pragma unroll
        for (int n = 0; n < 4; ++n) {
            const int col = tn + wc + n * 16 + fr;
            if (col < nstore) {
                f32x4 v = acc[m][n];
                float b = ADD_BIAS ? bias[col] : 0.0f;
#pragma unroll
                for (int j = 0; j < 4; ++j) {
                    const size_t idx = (size_t)(row0 + j) * ldc + col;
                    if (OUT_F32) ((float*)Cout)[idx] = v[j] + b;
                    else         ((unsigned short*)Cout)[idx] = f2bf(v[j] + b);
                }
            }
        }
    }
}

// ---------------- gating: per-token per-head softmaxes, write g over v-section ----------------
// C1 row layout: [0,1040) q-logits (16 heads x 65) | [1040,2064) k-logits | [2064,3088) v
__global__ __launch_bounds__(256) void k_gate(unsigned short* __restrict__ C1,
                                              const float* __restrict__ mask) {
    const int t    = blockIdx.x;
    const int wid  = threadIdx.x >> 6;
    const int lane = threadIdx.x & 63;
    unsigned short* row = C1 + (size_t)t * NTOT;
    const float mk = mask[t];
#pragma unroll
    for (int hh = 0; hh < 4; ++hh) {
        const int h = wid * 4 + hh;
        // q softmax over 65 slots -> last-slot probability
        float ql  = bf2f(row[h * 65 + lane]);
        float q64 = bf2f(row[h * 65 + 64]);
        float m = ql;
        for (int o = 32; o; o >>= 1) m = fmaxf(m, __shfl_xor(m, o));
        m = fmaxf(m, q64);
        float e = __expf(ql - m);
        float s = e;
        for (int o = 32; o; o >>= 1) s += __shfl_xor(s, o);
        float e64 = __expf(q64 - m);
        s += e64;
        const float w = 2.0f * (1.0f - e64 / s);   // qk_weight
        // k softmax over 64 slots
        float kl = bf2f(row[NQ + h * 64 + lane]);
        float km = kl;
        for (int o = 32; o; o >>= 1) km = fmaxf(km, __shfl_xor(km, o));
        float ke = __expf(kl - km);
        float ks = ke;
        for (int o = 32; o; o >>= 1) ks += __shfl_xor(ks, o);
        const float ksm = ke / ks;
        // gate v in place
        const int vi = NQ + NK + h * 64 + lane;
        const float v = bf2f(row[vi]);
        row[vi] = f2bf(w * ksm * v * mk);
    }
}

extern "C" void kernel_launch(void* const* d_in, const int* in_sizes, int n_in,
                              void* d_out, int out_size, void* d_ws, size_t ws_size,
                              hipStream_t stream) {
    (void)in_sizes; (void)n_in; (void)out_size; (void)ws_size;
    const float* x  = (const float*)d_in[0];
    const float* am = (const float*)d_in[1];
    const float* Wq = (const float*)d_in[2];
    const float* Wk = (const float*)d_in[3];
    const float* Wv = (const float*)d_in[4];
    const float* Wo = (const float*)d_in[5];
    const float* bo = (const float*)d_in[6];
    // time_angle / head_time_delta collapse to the constant 2 (see analysis)

    char* ws = (char*)d_ws;
    unsigned short* xb   = (unsigned short*)(ws);                  // 16384x1024 bf16   (33,554,432 B)
    unsigned short* Wall = (unsigned short*)(ws + 33554432);       // 3200x1024 bf16    ( 6,553,600 B)
    unsigned short* Wob  = (unsigned short*)(ws + 40108032);       // 1024x1024 bf16    ( 2,097,152 B)
    unsigned short* C1   = (unsigned short*)(ws + 42205184);       // 16384x3088 bf16   (101,187,584 B)

    // casts
    k_cast<<<dim3(TOKENS * DIM / 4 / 256), 256, 0, stream>>>(x, xb, TOKENS * DIM / 4);
    k_build_wall<<<dim3(NPAD * DIM / 4 / 256), 256, 0, stream>>>(Wq, Wk, Wv, Wall);
    k_cast<<<dim3(DIM * DIM / 4 / 256), 256, 0, stream>>>(Wo, Wob, DIM * DIM / 4);

    // GEMM1: C1[16384,3088] = xb @ Wall^T  (compute 3200 cols, store 3088, bf16 out)
    k_gemm<0, 0><<<dim3(NPAD / 128, TOKENS / 128), 256, 0, stream>>>(
        xb, DIM, Wall, DIM, C1, NTOT, NTOT, nullptr, DIM);

    // gating softmaxes, writes g over the v-section of C1
    k_gate<<<dim3(TOKENS), 256, 0, stream>>>(C1, am);

    // GEMM2: out[16384,1024] = g @ Wo^T + bo  (A = C1 v-section, lda=3088, f32 out)
    k_gemm<1, 1><<<dim3(DIM / 128, TOKENS / 128), 256, 0, stream>>>(
        C1 + (NQ + NK), NTOT, Wob, DIM, d_out, DIM, DIM, bo, DIM);
}

// Round 2
// 313.656 us; speedup vs baseline: 1.0378x; 1.0378x over previous
//
#include <hip/hip_runtime.h>
#include <cstdint>

#define TOKENS 16384   // b*l = 4*4096
#define DIM 1024
#define NQ 1040        // 16 heads * 65 q-slots
#define NK 1024        // 16 * 64
#define NTOT 3088      // NQ + NK + NK (q | k | v)
#define NPAD 3200      // next multiple of 128

typedef __bf16 bf16_t;
typedef bf16_t bf16x8 __attribute__((ext_vector_type(8)));
typedef float f32x4 __attribute__((ext_vector_type(4)));

static __device__ __forceinline__ float bf2f(unsigned short u) {
    union { unsigned int i; float f; } v; v.i = ((unsigned int)u) << 16; return v.f;
}
static __device__ __forceinline__ unsigned short f2bf(float f) {
    unsigned int u = __float_as_uint(f);
    unsigned int r = u + 0x7FFFu + ((u >> 16) & 1u);   // RNE
    return (unsigned short)(r >> 16);
}

// async global->LDS, 16B per lane; LDS dest is wave-uniform base + lane*16B.
static __device__ __forceinline__ void gload_lds16(const void* g, void* l) {
    __builtin_amdgcn_global_load_lds(
        (__attribute__((address_space(1))) void*)(uintptr_t)g,
        (__attribute__((address_space(3))) void*)(unsigned int)(uintptr_t)l,
        16, 0, 0);
}

// ---------------- cast kernels ----------------
__global__ __launch_bounds__(256) void k_cast(const float* __restrict__ in,
                                              unsigned short* __restrict__ out, int n4) {
    int i = blockIdx.x * 256 + threadIdx.x;
    if (i >= n4) return;
    float4 v = ((const float4*)in)[i];
    ushort4 o;
    o.x = f2bf(v.x); o.y = f2bf(v.y); o.z = f2bf(v.z); o.w = f2bf(v.w);
    ((ushort4*)out)[i] = o;
}

// Build Wall[NPAD][DIM] bf16 = rows: Wq (1040) | Wk (1024) | Wv (1024) | zeros (112)
__global__ __launch_bounds__(256) void k_build_wall(const float* __restrict__ Wq,
                                                    const float* __restrict__ Wk,
                                                    const float* __restrict__ Wv,
                                                    unsigned short* __restrict__ Wall) {
    int i = blockIdx.x * 256 + threadIdx.x;       // over NPAD*DIM/4
    if (i >= NPAD * DIM / 4) return;
    int c4 = i & 255;          // DIM/4 = 256
    int r  = i >> 8;
    float4 v;
    if (r < NQ)              v = ((const float4*)Wq)[r * 256 + c4];
    else if (r < NQ + NK)    v = ((const float4*)Wk)[(r - NQ) * 256 + c4];
    else if (r < NTOT)       v = ((const float4*)Wv)[(r - (NQ + NK)) * 256 + c4];
    else                     v = make_float4(0.f, 0.f, 0.f, 0.f);
    ushort4 o;
    o.x = f2bf(v.x); o.y = f2bf(v.y); o.z = f2bf(v.z); o.w = f2bf(v.w);
    ((ushort4*)Wall)[i] = o;
}

// ---------------- bf16 MFMA GEMM: C[M,N] = A[M,K] * Bt[N,K]^T ----------------
// 128x128 tile, BK=32, 4 waves, global_load_lds staging (m97 structure)
// + bijective XCD-chunked block swizzle (m204): each XCD owns a contiguous
//   run of M-panels (all N-blocks), so its L2 holds ~4MB of A + all of B.
template<int ADD_BIAS, int OUT_F32>
__global__ __launch_bounds__(256) void k_gemm(const unsigned short* __restrict__ A, int lda,
                                              const unsigned short* __restrict__ Bt, int ldb,
                                              void* __restrict__ Cout, int ldc, int nstore,
                                              const float* __restrict__ bias, int K) {
    __shared__ unsigned short Al[128 * 32];
    __shared__ unsigned short Bl[128 * 32];
    const int tid  = threadIdx.x;
    const int wid  = tid >> 6;
    const int lane = tid & 63;

    // XCD-chunked bijective swizzle (consecutive dispatch ids round-robin XCDs)
    const int nbx = gridDim.x;
    const int nb  = nbx * gridDim.y;
    const int L   = blockIdx.y * nbx + blockIdx.x;
    const int q8  = nb >> 3, r8 = nb & 7;
    const int xcd = L & 7;
    const int idx = L >> 3;
    const int newid = (xcd < r8) ? xcd * (q8 + 1) + idx
                                 : r8 * (q8 + 1) + (xcd - r8) * q8 + idx;
    const int tm = (newid / nbx) * 128;   // M-panel (slow within an XCD chunk)
    const int tn = (newid % nbx) * 128;   // N-block (fast -> A-panel reuse in L2)

    // staging: each wave fills 2 chunks (16 rows x 32 cols) of A and of B
    const int srow = lane >> 2;            // 0..15
    const int scol = (lane & 3) * 8;       // 0,8,16,24
    const unsigned short* Ag0 = A + (size_t)(tm + wid * 32 + srow) * lda + scol;
    const unsigned short* Ag1 = Ag0 + (size_t)16 * lda;
    const unsigned short* Bg0 = Bt + (size_t)(tn + wid * 32 + srow) * ldb + scol;
    const unsigned short* Bg1 = Bg0 + (size_t)16 * ldb;
    unsigned short* Al0 = &Al[(wid * 2 + 0) * 512];
    unsigned short* Al1 = &Al[(wid * 2 + 1) * 512];
    unsigned short* Bl0 = &Bl[(wid * 2 + 0) * 512];
    unsigned short* Bl1 = &Bl[(wid * 2 + 1) * 512];

    const int fr = lane & 15;
    const int fq = lane >> 4;
    const int wr = (wid >> 1) * 64;
    const int wc = (wid & 1) * 64;

    f32x4 acc[4][4] = {};

    for (int k0 = 0; k0 < K; k0 += 32) {
        gload_lds16(Ag0 + k0, Al0);
        gload_lds16(Ag1 + k0, Al1);
        gload_lds16(Bg0 + k0, Bl0);
        gload_lds16(Bg1 + k0, Bl1);
        __syncthreads();   // drains vmcnt(0) -> LDS tiles complete
        bf16x8 af[4], bfv[4];
#pragma unroll
        for (int m = 0; m < 4; ++m)
            af[m] = *(const bf16x8*)&Al[(wr + m * 16 + fr) * 32 + fq * 8];
#pragma unroll
        for (int n = 0; n < 4; ++n)
            bfv[n] = *(const bf16x8*)&Bl[(wc + n * 16 + fr) * 32 + fq * 8];
#pragma unroll
        for (int m = 0; m < 4; ++m)
#pragma unroll
            for (int n = 0; n < 4; ++n)
                acc[m][n] = __builtin_amdgcn_mfma_f32_16x16x32_bf16(af[m], bfv[n], acc[m][n], 0, 0, 0);
        __syncthreads();
    }

#pragma unroll
    for (int m = 0; m < 4; ++m) {
        const int row0 = tm + wr + m * 16 + fq * 4;
#pragma unroll
        for (int n = 0; n < 4; ++n) {
            const int col = tn + wc + n * 16 + fr;
            if (col < nstore) {
                f32x4 v = acc[m][n];
                float b = ADD_BIAS ? bias[col] : 0.0f;
#pragma unroll
                for (int j = 0; j < 4; ++j) {
                    const size_t idx2 = (size_t)(row0 + j) * ldc + col;
                    if (OUT_F32) ((float*)Cout)[idx2] = v[j] + b;
                    else         ((unsigned short*)Cout)[idx2] = f2bf(v[j] + b);
                }
            }
        }
    }
}

// ---------------- gating: per-token per-head softmaxes, write g over v-section ----------------
// C1 row layout: [0,1040) q-logits (16 heads x 65) | [1040,2064) k-logits | [2064,3088) v
__global__ __launch_bounds__(256) void k_gate(unsigned short* __restrict__ C1,
                                              const float* __restrict__ mask) {
    const int t    = blockIdx.x;
    const int wid  = threadIdx.x >> 6;
    const int lane = threadIdx.x & 63;
    unsigned short* row = C1 + (size_t)t * NTOT;
    const float mk = mask[t];
#pragma unroll
    for (int hh = 0; hh < 4; ++hh) {
        const int h = wid * 4 + hh;
        // q softmax over 65 slots -> last-slot probability
        float ql  = bf2f(row[h * 65 + lane]);
        float q64 = bf2f(row[h * 65 + 64]);
        float m = ql;
        for (int o = 32; o; o >>= 1) m = fmaxf(m, __shfl_xor(m, o));
        m = fmaxf(m, q64);
        float e = __expf(ql - m);
        float s = e;
        for (int o = 32; o; o >>= 1) s += __shfl_xor(s, o);
        float e64 = __expf(q64 - m);
        s += e64;
        const float w = 2.0f * (1.0f - e64 / s);   // qk_weight
        // k softmax over 64 slots
        float kl = bf2f(row[NQ + h * 64 + lane]);
        float km = kl;
        for (int o = 32; o; o >>= 1) km = fmaxf(km, __shfl_xor(km, o));
        float ke = __expf(kl - km);
        float ks = ke;
        for (int o = 32; o; o >>= 1) ks += __shfl_xor(ks, o);
        const float ksm = ke / ks;
        // gate v in place
        const int vi = NQ + NK + h * 64 + lane;
        const float v = bf2f(row[vi]);
        row[vi] = f2bf(w * ksm * v * mk);
    }
}

extern "C" void kernel_launch(void* const* d_in, const int* in_sizes, int n_in,
                              void* d_out, int out_size, void* d_ws, size_t ws_size,
                              hipStream_t stream) {
    (void)in_sizes; (void)n_in; (void)out_size; (void)ws_size;
    const float* x  = (const float*)d_in[0];
    const float* am = (const float*)d_in[1];
    const float* Wq = (const float*)d_in[2];
    const float* Wk = (const float*)d_in[3];
    const float* Wv = (const float*)d_in[4];
    const float* Wo = (const float*)d_in[5];
    const float* bo = (const float*)d_in[6];
    // time_angle / head_time_delta collapse to the constant 2 (see analysis)

    char* ws = (char*)d_ws;
    unsigned short* xb   = (unsigned short*)(ws);                  // 16384x1024 bf16   (33,554,432 B)
    unsigned short* Wall = (unsigned short*)(ws + 33554432);       // 3200x1024 bf16    ( 6,553,600 B)
    unsigned short* Wob  = (unsigned short*)(ws + 40108032);       // 1024x1024 bf16    ( 2,097,152 B)
    unsigned short* C1   = (unsigned short*)(ws + 42205184);       // 16384x3088 bf16   (101,187,584 B)

    // casts
    k_cast<<<dim3(TOKENS * DIM / 4 / 256), 256, 0, stream>>>(x, xb, TOKENS * DIM / 4);
    k_build_wall<<<dim3(NPAD * DIM / 4 / 256), 256, 0, stream>>>(Wq, Wk, Wv, Wall);
    k_cast<<<dim3(DIM * DIM / 4 / 256), 256, 0, stream>>>(Wo, Wob, DIM * DIM / 4);

    // GEMM1: C1[16384,3088] = xb @ Wall^T  (compute 3200 cols, store 3088, bf16 out)
    k_gemm<0, 0><<<dim3(NPAD / 128, TOKENS / 128), 256, 0, stream>>>(
        xb, DIM, Wall, DIM, C1, NTOT, NTOT, nullptr, DIM);

    // gating softmaxes, writes g over the v-section of C1
    k_gate<<<dim3(TOKENS), 256, 0, stream>>>(C1, am);

    // GEMM2: out[16384,1024] = g @ Wo^T + bo  (A = C1 v-section, lda=3088, f32 out)
    k_gemm<1, 1><<<dim3(DIM / 128, TOKENS / 128), 256, 0, stream>>>(
        C1 + (NQ + NK), NTOT, Wob, DIM, d_out, DIM, DIM, bo, DIM);
}

// Round 3
// 254.018 us; speedup vs baseline: 1.2814x; 1.2348x over previous
//
#include <hip/hip_runtime.h>
#include <cstdint>

#define TOKENS 16384   // b*l = 4*4096
#define DIM 1024
#define NQ 1040        // 16 heads * 65 q-slots
#define NK 1024        // 16 * 64
#define NTOT 3088      // NQ + NK + NK (q | k | v)
#define NPAD 3328      // next multiple of 256
#define NKT 16         // K = 1024 = 16 K-tiles of 64

typedef __bf16 bf16_t;
typedef bf16_t bf16x8 __attribute__((ext_vector_type(8)));
typedef float f32x4 __attribute__((ext_vector_type(4)));

static __device__ __forceinline__ float bf2f(unsigned short u) {
    union { unsigned int i; float f; } v; v.i = ((unsigned int)u) << 16; return v.f;
}
static __device__ __forceinline__ unsigned short f2bf(float f) {
    unsigned int u = __float_as_uint(f);
    unsigned int r = u + 0x7FFFu + ((u >> 16) & 1u);   // RNE
    return (unsigned short)(r >> 16);
}

// async global->LDS, 16B/lane; LDS dest is wave-uniform base + lane*16B (linear).
static __device__ __forceinline__ void gload_lds16(const void* g, void* l) {
    __builtin_amdgcn_global_load_lds(
        (__attribute__((address_space(1))) void*)(uintptr_t)g,
        (__attribute__((address_space(3))) void*)(unsigned int)(uintptr_t)l,
        16, 0, 0);
}

// ---------------- cast kernels ----------------
__global__ __launch_bounds__(256) void k_cast(const float* __restrict__ in,
                                              unsigned short* __restrict__ out, int n4) {
    int i = blockIdx.x * 256 + threadIdx.x;
    if (i >= n4) return;
    float4 v = ((const float4*)in)[i];
    ushort4 o;
    o.x = f2bf(v.x); o.y = f2bf(v.y); o.z = f2bf(v.z); o.w = f2bf(v.w);
    ((ushort4*)out)[i] = o;
}

// Wall[NPAD][DIM] bf16 = rows: Wq (1040) | Wk (1024) | Wv (1024) | zeros (240)
__global__ __launch_bounds__(256) void k_build_wall(const float* __restrict__ Wq,
                                                    const float* __restrict__ Wk,
                                                    const float* __restrict__ Wv,
                                                    unsigned short* __restrict__ Wall) {
    int i = blockIdx.x * 256 + threadIdx.x;       // over NPAD*DIM/4
    if (i >= NPAD * DIM / 4) return;
    int c4 = i & 255;          // DIM/4 = 256
    int r  = i >> 8;
    float4 v;
    if (r < NQ)              v = ((const float4*)Wq)[r * 256 + c4];
    else if (r < NQ + NK)    v = ((const float4*)Wk)[(r - NQ) * 256 + c4];
    else if (r < NTOT)       v = ((const float4*)Wv)[(r - (NQ + NK)) * 256 + c4];
    else                     v = make_float4(0.f, 0.f, 0.f, 0.f);
    ushort4 o;
    o.x = f2bf(v.x); o.y = f2bf(v.y); o.z = f2bf(v.z); o.w = f2bf(v.w);
    ((ushort4*)Wall)[i] = o;
}

// ============ 256x256x(BK=64) 8-phase bf16 GEMM: C[M,N] = A[M,K] * Bt[N,K]^T ============
// 8 waves (2M x 4N), 512 thr, LDS 128KB = 2buf x (A 32KB + B 32KB), one K-tile each.
// Swizzle: logical 16B slot s of row r stored at phys slot s^(r&7); staging pre-swizzles
// the GLOBAL source address (LDS dest stays linear for global_load_lds), reads XOR.
// Schedule per K-tile kt (buf kt&1): P0 reads A[mh0]+B[nh0], stages A-h0(kt+1);
// P1 reads B[nh1], stages A-h1(kt+1); P2 reads A[mh1], stages B-h0(kt+2);
// P3 (no reads), stages B-h1(kt+2), vmcnt(4) [vmcnt(0) for kt>=14]. 2 raw barriers/phase.
template<int ADD_BIAS, int OUT_F32>
__global__ __launch_bounds__(512, 2) void k_gemm256(const unsigned short* __restrict__ A, int lda,
                                                    const unsigned short* __restrict__ Bt, int ldb,
                                                    void* __restrict__ Cout, int ldc, int nstore,
                                                    const float* __restrict__ bias) {
    __shared__ char smem[131072];
    const int tid  = threadIdx.x;
    const int wid  = tid >> 6;          // 0..7
    const int lane = tid & 63;
    const int wm = wid >> 2;            // 0..1  (M half)
    const int wn = wid & 3;             // 0..3  (N quarter)
    const int fr = lane & 15;
    const int fq = lane >> 4;
    const int fr7 = fr & 7;
    const int srow8  = lane >> 3;                        // staging row-in-chunk
    const int cperm8 = ((lane & 7) ^ srow8) * 8;         // staging col perm (elements)

    // XCD-chunked bijective swizzle (nb divisible by 8 for both GEMMs)
    const int nbx = gridDim.x;
    const int nb  = nbx * gridDim.y;
    const int L   = blockIdx.y * nbx + blockIdx.x;
    const int q8  = nb >> 3;
    const int newid = (L & 7) * q8 + (L >> 3);
    const int tm = (newid / nbx) * 256;
    const int tn = (newid % nbx) * 256;

    // ---- staging helpers (uniform LDS dst; per-lane pre-swizzled global src) ----
#define STAGE(ptr, ld, tile0, kt2, h, matbase)                                              \
    {                                                                                        \
        _Pragma("unroll")                                                                    \
        for (int j = 0; j < 2; ++j) {                                                        \
            const int c = wid * 2 + j;                                                       \
            const unsigned short* src = (ptr) +                                              \
                (size_t)((tile0) + (h) * 128 + c * 8 + srow8) * (ld) + (kt2) * 64 + cperm8;  \
            char* dst = (char*)smem + ((((kt2) & 1) << 16) | (matbase) | ((h) << 14) | (c << 10)); \
            gload_lds16(src, dst);                                                           \
        }                                                                                    \
    }
#define STAGE_A(kt2, h) STAGE(A, lda, tm, kt2, h, 0)
#define STAGE_B(kt2, h) STAGE(Bt, ldb, tn, kt2, h, 32768)

    // ---- fragment ds_read address components ----
    const int sx0 = ((0 + fq) ^ fr7) << 4;              // ks=0 16B slot (swizzled)
    const int sx1 = ((4 + fq) ^ fr7) << 4;              // ks=1
    const int aoff = (wm << 14) + (fr << 7);
    const int boff = 32768 + ((wn >> 1) << 14) + ((((wn & 1) * 64) + fr) << 7);

    bf16x8 a[4][2], b0[2][2], b1[2][2];
    f32x4 acc[8][4] = {};

#define READ_A(kb, mh)                                                                       \
    { _Pragma("unroll")                                                                      \
      for (int i = 0; i < 4; ++i) {                                                          \
        a[i][0] = *(const bf16x8*)(smem + (kb) + aoff + (((mh) * 64 + i * 16) << 7) + sx0);  \
        a[i][1] = *(const bf16x8*)(smem + (kb) + aoff + (((mh) * 64 + i * 16) << 7) + sx1);  \
      } }
#define READ_B(kb, nh, breg)                                                                 \
    { _Pragma("unroll")                                                                      \
      for (int n2 = 0; n2 < 2; ++n2) {                                                       \
        breg[n2][0] = *(const bf16x8*)(smem + (kb) + boff + ((((nh) * 2 + n2) * 16) << 7) + sx0); \
        breg[n2][1] = *(const bf16x8*)(smem + (kb) + boff + ((((nh) * 2 + n2) * 16) << 7) + sx1); \
      } }
#define MFMA_Q(mh, nh, breg)                                                                 \
    { _Pragma("unroll")                                                                      \
      for (int i = 0; i < 4; ++i)                                                            \
        _Pragma("unroll")                                                                    \
        for (int n2 = 0; n2 < 2; ++n2) {                                                     \
          acc[(mh) * 4 + i][(nh) * 2 + n2] = __builtin_amdgcn_mfma_f32_16x16x32_bf16(        \
              a[i][0], breg[n2][0], acc[(mh) * 4 + i][(nh) * 2 + n2], 0, 0, 0);              \
          acc[(mh) * 4 + i][(nh) * 2 + n2] = __builtin_amdgcn_mfma_f32_16x16x32_bf16(        \
              a[i][1], breg[n2][1], acc[(mh) * 4 + i][(nh) * 2 + n2], 0, 0, 0);              \
        } }
#define SYNC_PRE()                                             \
    __builtin_amdgcn_s_barrier();                              \
    asm volatile("s_waitcnt lgkmcnt(0)" ::: "memory");         \
    __builtin_amdgcn_sched_barrier(0);                         \
    __builtin_amdgcn_s_setprio(1);
#define SYNC_POST()                                            \
    __builtin_amdgcn_s_setprio(0);                             \
    __builtin_amdgcn_s_barrier();

    // ---- prologue: kt0 fully + kt1's B halves; drain the kt0 stages ----
    STAGE_A(0, 0); STAGE_A(0, 1); STAGE_B(0, 0); STAGE_B(0, 1);
    STAGE_B(1, 0); STAGE_B(1, 1);
    asm volatile("s_waitcnt vmcnt(4)" ::: "memory");
    __builtin_amdgcn_s_barrier();

    for (int kt = 0; kt < NKT; ++kt) {
        const int kb = (kt & 1) << 16;
        // ---- P0 ----
        READ_A(kb, 0);
        READ_B(kb, 0, b0);
        if (kt < NKT - 1) STAGE_A(kt + 1, 0);
        asm volatile("s_waitcnt lgkmcnt(8)" ::: "memory");
        SYNC_PRE(); MFMA_Q(0, 0, b0); SYNC_POST();
        // ---- P1 ----
        READ_B(kb, 1, b1);
        if (kt < NKT - 1) STAGE_A(kt + 1, 1);
        SYNC_PRE(); MFMA_Q(0, 1, b1); SYNC_POST();
        // ---- P2 ----
        READ_A(kb, 1);
        if (kt < NKT - 2) STAGE_B(kt + 2, 0);
        SYNC_PRE(); MFMA_Q(1, 1, b1); SYNC_POST();
        // ---- P3 (no ds_read; uses regs a[mh1], b0) ----
        if (kt < NKT - 2) STAGE_B(kt + 2, 1);
        __builtin_amdgcn_s_barrier();
        __builtin_amdgcn_s_setprio(1); MFMA_Q(1, 0, b0); __builtin_amdgcn_s_setprio(0);
        if (kt < NKT - 2) { asm volatile("s_waitcnt vmcnt(4)" ::: "memory"); }
        else              { asm volatile("s_waitcnt vmcnt(0)" ::: "memory"); }
        __builtin_amdgcn_s_barrier();
    }

    // ---- epilogue: C write ----
#pragma unroll
    for (int mq = 0; mq < 8; ++mq) {
        const int row0 = tm + wm * 128 + mq * 16 + fq * 4;
#pragma unroll
        for (int nf = 0; nf < 4; ++nf) {
            const int col = tn + wn * 64 + nf * 16 + fr;
            if (col < nstore) {
                f32x4 v = acc[mq][nf];
                const float bb = ADD_BIAS ? bias[col] : 0.0f;
#pragma unroll
                for (int j = 0; j < 4; ++j) {
                    const size_t idx = (size_t)(row0 + j) * ldc + col;
                    if (OUT_F32) ((float*)Cout)[idx] = v[j] + bb;
                    else         ((unsigned short*)Cout)[idx] = f2bf(v[j] + bb);
                }
            }
        }
    }
#undef STAGE
#undef STAGE_A
#undef STAGE_B
#undef READ_A
#undef READ_B
#undef MFMA_Q
#undef SYNC_PRE
#undef SYNC_POST
}

// ---------------- gating: per-token per-head softmaxes, write g over v-section ----------------
__global__ __launch_bounds__(256) void k_gate(unsigned short* __restrict__ C1,
                                              const float* __restrict__ mask) {
    const int t    = blockIdx.x;
    const int wid  = threadIdx.x >> 6;
    const int lane = threadIdx.x & 63;
    unsigned short* row = C1 + (size_t)t * NTOT;
    const float mk = mask[t];
#pragma unroll
    for (int hh = 0; hh < 4; ++hh) {
        const int h = wid * 4 + hh;
        float ql  = bf2f(row[h * 65 + lane]);
        float q64 = bf2f(row[h * 65 + 64]);
        float m = ql;
        for (int o = 32; o; o >>= 1) m = fmaxf(m, __shfl_xor(m, o));
        m = fmaxf(m, q64);
        float e = __expf(ql - m);
        float s = e;
        for (int o = 32; o; o >>= 1) s += __shfl_xor(s, o);
        float e64 = __expf(q64 - m);
        s += e64;
        const float w = 2.0f * (1.0f - e64 / s);   // qk_weight
        float kl = bf2f(row[NQ + h * 64 + lane]);
        float km = kl;
        for (int o = 32; o; o >>= 1) km = fmaxf(km, __shfl_xor(km, o));
        float ke = __expf(kl - km);
        float ks = ke;
        for (int o = 32; o; o >>= 1) ks += __shfl_xor(ks, o);
        const float ksm = ke / ks;
        const int vi = NQ + NK + h * 64 + lane;
        const float v = bf2f(row[vi]);
        row[vi] = f2bf(w * ksm * v * mk);
    }
}

extern "C" void kernel_launch(void* const* d_in, const int* in_sizes, int n_in,
                              void* d_out, int out_size, void* d_ws, size_t ws_size,
                              hipStream_t stream) {
    (void)in_sizes; (void)n_in; (void)out_size; (void)ws_size;
    const float* x  = (const float*)d_in[0];
    const float* am = (const float*)d_in[1];
    const float* Wq = (const float*)d_in[2];
    const float* Wk = (const float*)d_in[3];
    const float* Wv = (const float*)d_in[4];
    const float* Wo = (const float*)d_in[5];
    const float* bo = (const float*)d_in[6];
    // time_angle / head_time_delta collapse to the constant 2 (see round-0 analysis)

    char* ws = (char*)d_ws;
    unsigned short* xb   = (unsigned short*)(ws);                  // 16384x1024 bf16   33,554,432 B
    unsigned short* Wall = (unsigned short*)(ws + 33554432);       // 3328x1024 bf16     6,815,744 B
    unsigned short* Wob  = (unsigned short*)(ws + 40370176);       // 1024x1024 bf16     2,097,152 B
    unsigned short* C1   = (unsigned short*)(ws + 42467328);       // 16384x3088 bf16  101,187,584 B

    k_cast<<<dim3(TOKENS * DIM / 4 / 256), 256, 0, stream>>>(x, xb, TOKENS * DIM / 4);
    k_build_wall<<<dim3(NPAD * DIM / 4 / 256), 256, 0, stream>>>(Wq, Wk, Wv, Wall);
    k_cast<<<dim3(DIM * DIM / 4 / 256), 256, 0, stream>>>(Wo, Wob, DIM * DIM / 4);

    // GEMM1: C1[16384,3088] = xb @ Wall^T  (compute 3328 cols, store 3088, bf16 out)
    k_gemm256<0, 0><<<dim3(NPAD / 256, TOKENS / 256), 512, 0, stream>>>(
        xb, DIM, Wall, DIM, C1, NTOT, NTOT, nullptr);

    k_gate<<<dim3(TOKENS), 256, 0, stream>>>(C1, am);

    // GEMM2: out[16384,1024] = g @ Wo^T + bo  (A = C1 v-section, lda=3088, f32 out)
    k_gemm256<1, 1><<<dim3(DIM / 256, TOKENS / 256), 512, 0, stream>>>(
        C1 + (NQ + NK), NTOT, Wob, DIM, d_out, DIM, DIM, bo);
}